// Round 2
// baseline (559.459 us; speedup 1.0000x reference)
//
#include <hip/hip_runtime.h>
#include <stdint.h>

// ---------------------------------------------------------------------------
// LDAM: pooled dual-modality non-local attention + BN + residual + 2x upsample
// B=8, C=256, IC=128 -> pooled 64x64 (Nq=4096), sub-sampled 32x32 (Nkv=1024).
// Score path in split-bf16 (hi+lo); value path plain bf16.
// Round 2: no-max softmax (range-safe: scores max ~23, exp fits fp32/bf16),
// KV-split attention (16 waves/CU), register-weight convs (no barriers),
// vectorized pool I/O.
// ---------------------------------------------------------------------------

typedef unsigned short u16;
typedef short bf16x8 __attribute__((ext_vector_type(8)));
typedef float f32x4 __attribute__((ext_vector_type(4)));

#define MFMA16(a, b, c) __builtin_amdgcn_mfma_f32_16x16x32_bf16(a, b, c, 0, 0, 0)

__device__ __forceinline__ u16 f2bf(float x) {
    union { float f; unsigned int u; } v; v.f = x;
    unsigned int u = v.u;
    unsigned int r = u + 0x7fffu + ((u >> 16) & 1u);   // round-nearest-even
    return (u16)(r >> 16);
}
__device__ __forceinline__ float bf2f(u16 h) {
    union { unsigned int u; float f; } v; v.u = ((unsigned int)h) << 16;
    return v.f;
}

// ---------------------------------------------------------------------------
// K0: zero the BN accumulator (ws re-poisoned 0xAA before every call)
// ---------------------------------------------------------------------------
__global__ void zero_kernel(float* __restrict__ p, int n) {
    int i = blockIdx.x * 256 + threadIdx.x;
    if (i < n) p[i] = 0.0f;
}

// ---------------------------------------------------------------------------
// K1: 2x2 maxpool + NCHW -> [pos, c] transpose + hi/lo bf16 split.
// grid = B*64*4 (b, h2 row, 64-channel tile); block = 256.
// ---------------------------------------------------------------------------
__global__ __launch_bounds__(256) void pool_transpose_kernel(
    const float* __restrict__ x, u16* __restrict__ ohi, u16* __restrict__ olo) {
    __shared__ float tile[64][65];  // [w2][c_local], +1 pad
    int bx = blockIdx.x;
    int ct = bx & 3, h2 = (bx >> 2) & 63, b = bx >> 8;
    int tid = threadIdx.x;
    int col = tid & 127;
    int chalf = tid >> 7;

    long base_in = (((long)b * 256 + ct * 64) * 128 + 2 * h2) * 128;
#pragma unroll 4
    for (int i = 0; i < 32; i++) {
        int c_l = i * 2 + chalf;
        const float* p = x + base_in + (long)c_l * 16384;
        float m = fmaxf(p[col], p[128 + col]);          // vertical max
        float o = __shfl_xor(m, 1);                     // horizontal partner
        m = fmaxf(m, o);
        if ((col & 1) == 0) tile[col >> 1][c_l] = m;
    }
    __syncthreads();
    long obase = ((long)b * 4096 + h2 * 64) * 256 + ct * 64;
#pragma unroll 4
    for (int i = 0; i < 8; i++) {
        int idx = i * 512 + tid * 2;
        int w2 = idx >> 6, c_l = idx & 63;
        float v0 = tile[w2][c_l], v1 = tile[w2][c_l + 1];
        u16 h0 = f2bf(v0), h1 = f2bf(v1);
        ushort2 hh; hh.x = h0; hh.y = h1;
        ushort2 ll; ll.x = f2bf(v0 - bf2f(h0)); ll.y = f2bf(v1 - bf2f(h1));
        long oi = obase + (long)w2 * 256 + c_l;
        *(ushort2*)&ohi[oi] = hh;
        *(ushort2*)&olo[oi] = ll;
    }
}

// ---------------------------------------------------------------------------
// K2: split the four weight matrices into bf16 hi/lo planes
// ---------------------------------------------------------------------------
__global__ void wsplit_kernel(const float* __restrict__ tw, const float* __restrict__ pw,
                              const float* __restrict__ gw, const float* __restrict__ ww,
                              u16* __restrict__ planes) {
    int idx = blockIdx.x * 256 + threadIdx.x;   // 131072 = 4*32768
    int m = idx >> 15, e = idx & 32767;
    const float* src = (m == 0) ? tw : (m == 1) ? pw : (m == 2) ? gw : ww;
    float v = src[e];
    u16 h = f2bf(v);
    planes[m * 65536 + e] = h;
    planes[m * 65536 + 32768 + e] = f2bf(v - bf2f(h));
}

// ---------------------------------------------------------------------------
// K3: 1x1 conv as GEMM, weights register-resident (no LDS, no barriers).
// out[M,O] = A[M,K]*W[O,K]^T + bias. RG row-groups of 16 per wave.
// OMODE: 0 bf16 out, 1 bf16 hi+lo out, 2 fp32 out.
// block = 256 (4 waves), block rows = 64*RG.
// ---------------------------------------------------------------------------
template <int K, int O, bool SPLIT, int OMODE, int RG>
__global__ __launch_bounds__(256) void conv1x1_kernel(
    const u16* __restrict__ Ahi, const u16* __restrict__ Alo,
    const u16* __restrict__ Whi, const u16* __restrict__ Wlo,
    const float* __restrict__ bias,
    u16* __restrict__ out_hi, u16* __restrict__ out_lo, float* __restrict__ out_f) {
    constexpr int NT = O / 16;
    int tid = threadIdx.x;
    int wave = tid >> 6, lane = tid & 63, quad = lane >> 4, l16 = lane & 15;
    long mbase = (long)blockIdx.x * (64 * RG) + wave * (16 * RG);

    f32x4 acc[RG][NT];
#pragma unroll
    for (int rg = 0; rg < RG; rg++)
#pragma unroll
        for (int nt = 0; nt < NT; nt++)
#pragma unroll
            for (int r = 0; r < 4; r++) acc[rg][nt][r] = 0.0f;

#pragma unroll
    for (int kc = 0; kc < K / 32; kc++) {
        bf16x8 ah[RG], al[RG];
#pragma unroll
        for (int rg = 0; rg < RG; rg++) {
            long arow = mbase + rg * 16 + l16;
            ah[rg] = *(const bf16x8*)&Ahi[arow * K + kc * 32 + quad * 8];
            if (SPLIT) al[rg] = *(const bf16x8*)&Alo[arow * K + kc * 32 + quad * 8];
        }
#pragma unroll
        for (int nt = 0; nt < NT; nt++) {
            long wrow = (long)(nt * 16 + l16) * K + kc * 32 + quad * 8;
            bf16x8 bh = *(const bf16x8*)&Whi[wrow];
            bf16x8 bl;
            if (SPLIT) bl = *(const bf16x8*)&Wlo[wrow];
#pragma unroll
            for (int rg = 0; rg < RG; rg++) {
                acc[rg][nt] = MFMA16(ah[rg], bh, acc[rg][nt]);
                if (SPLIT) {
                    acc[rg][nt] = MFMA16(ah[rg], bl, acc[rg][nt]);
                    acc[rg][nt] = MFMA16(al[rg], bh, acc[rg][nt]);
                }
            }
        }
    }

#pragma unroll
    for (int rg = 0; rg < RG; rg++)
#pragma unroll
        for (int nt = 0; nt < NT; nt++) {
            int colo = nt * 16 + l16;
            float bv = bias[colo];
#pragma unroll
            for (int r = 0; r < 4; r++) {
                long row = mbase + rg * 16 + quad * 4 + r;
                float v = acc[rg][nt][r] + bv;
                long idx = row * O + colo;
                if (OMODE == 2) {
                    out_f[idx] = v;
                } else if (OMODE == 0) {
                    out_hi[idx] = f2bf(v);
                } else {
                    u16 h = f2bf(v);
                    out_hi[idx] = h;
                    out_lo[idx] = f2bf(v - bf2f(h));
                }
            }
        }
}

// ---------------------------------------------------------------------------
// K3b: fused phi (split, hi/lo out) + g (plain, bf16 out) conv over event_p.
// K=256, O=128, RG=2, grid 256, block 256.
// ---------------------------------------------------------------------------
__global__ __launch_bounds__(256) void conv_phig_kernel(
    const u16* __restrict__ Ahi, const u16* __restrict__ Alo,
    const u16* __restrict__ Wph, const u16* __restrict__ Wpl,
    const u16* __restrict__ Wgh,
    const float* __restrict__ phi_b, const float* __restrict__ g_b,
    u16* __restrict__ phi_hi, u16* __restrict__ phi_lo, u16* __restrict__ gout) {
    int tid = threadIdx.x;
    int wave = tid >> 6, lane = tid & 63, quad = lane >> 4, l16 = lane & 15;
    long mbase = (long)blockIdx.x * 128 + wave * 32;

    f32x4 ap[2][8], ag[2][8];
#pragma unroll
    for (int rg = 0; rg < 2; rg++)
#pragma unroll
        for (int nt = 0; nt < 8; nt++)
#pragma unroll
            for (int r = 0; r < 4; r++) { ap[rg][nt][r] = 0.0f; ag[rg][nt][r] = 0.0f; }

#pragma unroll
    for (int kc = 0; kc < 8; kc++) {
        bf16x8 ah[2], al[2];
#pragma unroll
        for (int rg = 0; rg < 2; rg++) {
            long arow = mbase + rg * 16 + l16;
            ah[rg] = *(const bf16x8*)&Ahi[arow * 256 + kc * 32 + quad * 8];
            al[rg] = *(const bf16x8*)&Alo[arow * 256 + kc * 32 + quad * 8];
        }
#pragma unroll
        for (int nt = 0; nt < 8; nt++) {
            long wrow = (long)(nt * 16 + l16) * 256 + kc * 32 + quad * 8;
            bf16x8 bph = *(const bf16x8*)&Wph[wrow];
            bf16x8 bpl = *(const bf16x8*)&Wpl[wrow];
            bf16x8 bgh = *(const bf16x8*)&Wgh[wrow];
#pragma unroll
            for (int rg = 0; rg < 2; rg++) {
                ap[rg][nt] = MFMA16(ah[rg], bph, ap[rg][nt]);
                ap[rg][nt] = MFMA16(ah[rg], bpl, ap[rg][nt]);
                ap[rg][nt] = MFMA16(al[rg], bph, ap[rg][nt]);
                ag[rg][nt] = MFMA16(ah[rg], bgh, ag[rg][nt]);
            }
        }
    }

#pragma unroll
    for (int rg = 0; rg < 2; rg++)
#pragma unroll
        for (int nt = 0; nt < 8; nt++) {
            int colo = nt * 16 + l16;
            float pb = phi_b[colo], gb = g_b[colo];
#pragma unroll
            for (int r = 0; r < 4; r++) {
                long row = mbase + rg * 16 + quad * 4 + r;
                long idx = row * 128 + colo;
                float vp = ap[rg][nt][r] + pb;
                u16 h = f2bf(vp);
                phi_hi[idx] = h;
                phi_lo[idx] = f2bf(vp - bf2f(h));
                gout[idx] = f2bf(ag[rg][nt][r] + gb);
            }
        }
}

// ---------------------------------------------------------------------------
// K4: sub-sample pool phi -> K layout [B,1024,128] hi/lo, vectorized bf16x8.
// grid 512, block 256: thread handles 8 channels of one kv.
// ---------------------------------------------------------------------------
__global__ __launch_bounds__(256) void pool_phiK_kernel(
    const u16* __restrict__ fhi, const u16* __restrict__ flo,
    u16* __restrict__ khi, u16* __restrict__ klo) {
    int idx = blockIdx.x * 256 + threadIdx.x;   // 131072 = 8*1024*16
    int c8 = (idx & 15) * 8;
    int kv = (idx >> 4) & 1023;
    int b = idx >> 14;
    int h4 = kv >> 5, w4 = kv & 31;
    long p00 = ((long)b * 4096 + (2 * h4) * 64 + 2 * w4) * 128 + c8;
    bf16x8 h0 = *(const bf16x8*)&fhi[p00];
    bf16x8 h1 = *(const bf16x8*)&fhi[p00 + 128];
    bf16x8 h2 = *(const bf16x8*)&fhi[p00 + 8192];
    bf16x8 h3 = *(const bf16x8*)&fhi[p00 + 8320];
    bf16x8 l0 = *(const bf16x8*)&flo[p00];
    bf16x8 l1 = *(const bf16x8*)&flo[p00 + 128];
    bf16x8 l2 = *(const bf16x8*)&flo[p00 + 8192];
    bf16x8 l3 = *(const bf16x8*)&flo[p00 + 8320];
    bf16x8 oh, ol;
#pragma unroll
    for (int e = 0; e < 8; e++) {
        float v = fmaxf(fmaxf(bf2f((u16)h0[e]) + bf2f((u16)l0[e]),
                              bf2f((u16)h1[e]) + bf2f((u16)l1[e])),
                        fmaxf(bf2f((u16)h2[e]) + bf2f((u16)l2[e]),
                              bf2f((u16)h3[e]) + bf2f((u16)l3[e])));
        u16 h = f2bf(v);
        oh[e] = (short)h;
        ol[e] = (short)f2bf(v - bf2f(h));
    }
    long oi = ((long)b * 1024 + kv) * 128 + c8;
    *(bf16x8*)&khi[oi] = oh;
    *(bf16x8*)&klo[oi] = ol;
}

// ---------------------------------------------------------------------------
// K5: sub-sample pool g + transpose -> V^T [B,128,1024] bf16
// ---------------------------------------------------------------------------
__global__ __launch_bounds__(256) void pool_gVt_kernel(
    const u16* __restrict__ g, u16* __restrict__ vt) {
    __shared__ u16 t[64][65];   // [c_l][kv_l]
    int bx = blockIdx.x;
    int ct = bx & 1, kvt = (bx >> 1) & 15, b = bx >> 5;
    int tid = threadIdx.x;
#pragma unroll 4
    for (int i = 0; i < 16; i++) {
        int idx = i * 256 + tid;
        int kv_l = idx >> 6, c_l = idx & 63;
        int kv = kvt * 64 + kv_l;
        int h4 = kv >> 5, w4 = kv & 31;
        long p00 = ((long)b * 4096 + (2 * h4) * 64 + 2 * w4) * 128 + ct * 64 + c_l;
        float v = fmaxf(fmaxf(bf2f(g[p00]), bf2f(g[p00 + 128])),
                        fmaxf(bf2f(g[p00 + 8192]), bf2f(g[p00 + 8192 + 128])));
        t[c_l][kv_l] = f2bf(v);
    }
    __syncthreads();
    long ob = ((long)b * 128 + ct * 64) * 1024 + kvt * 64;
#pragma unroll 4
    for (int i = 0; i < 16; i++) {
        int idx = i * 256 + tid;
        int c_l = idx >> 6, kv_l = idx & 63;
        vt[ob + (long)c_l * 1024 + kv_l] = t[c_l][kv_l];
    }
}

// ---------------------------------------------------------------------------
// K6: fused attention, NO-MAX softmax (scores max ~23 -> exp fits fp32/bf16;
// partials over disjoint KV merge by pure addition). 512 threads = 8 waves:
// waves 0-3 (group 0) take kv [0,512), waves 4-7 (group 1) take [512,1024)
// for the same 64 Q rows; merge via LDS at the end. KV tile 32 per group.
// grid = 512 (b = bx&7 XCD swizzle), LDS = 64 KB exactly -> 2 blocks/CU.
// ---------------------------------------------------------------------------
__global__ __launch_bounds__(512, 4) void attn_kernel(
    const u16* __restrict__ th, const u16* __restrict__ tl,
    const u16* __restrict__ khi, const u16* __restrict__ klo,
    const u16* __restrict__ vt, u16* __restrict__ y) {
    __shared__ u16 Kh[2][32][136];   // 17408 B
    __shared__ u16 Kl[2][32][136];   // 17408 B
    __shared__ u16 Vt[2][128][40];   // 20480 B
    __shared__ u16 Pl[8][16][40];    // 10240 B   => 65536 B total

    int bx = blockIdx.x;
    int b = bx & 7, qt = bx >> 3;
    int tid = threadIdx.x;
    int w = tid >> 6, g = w >> 2, wsub = w & 3;
    int lane = tid & 63, quad = lane >> 4, l16 = lane & 15;
    int qbase = qt * 64 + wsub * 16;

    // Q fragments (hi+lo), reused for all KV tiles
    bf16x8 qh[4], ql[4];
    long tb = ((long)b * 4096 + qbase + l16) * 128;
#pragma unroll
    for (int kc = 0; kc < 4; kc++) {
        qh[kc] = *(const bf16x8*)&th[tb + kc * 32 + quad * 8];
        ql[kc] = *(const bf16x8*)&tl[tb + kc * 32 + quad * 8];
    }

    f32x4 o[8];
#pragma unroll
    for (int t2 = 0; t2 < 8; t2++)
#pragma unroll
        for (int r = 0; r < 4; r++) o[t2][r] = 0.0f;
    float lp[4] = {0.0f, 0.0f, 0.0f, 0.0f};

#pragma unroll 1
    for (int it = 0; it < 16; it++) {
        __syncthreads();
        // stage both groups' KV tiles (32 kv each): slot s <- kv base s*512+it*32
#pragma unroll
        for (int j = 0; j < 2; j++) {
            int c0 = j * 512 + tid;
            int row = (c0 >> 4) & 31, ko = (c0 & 15) * 8;
            long src = ((long)b * 1024 + j * 512 + it * 32 + row) * 128 + ko;
            *(uint4*)&Kh[j][row][ko] = *(const uint4*)&khi[src];
            *(uint4*)&Kl[j][row][ko] = *(const uint4*)&klo[src];
        }
#pragma unroll
        for (int j = 0; j < 2; j++) {
            int c0 = j * 512 + tid;
            int crow = (c0 >> 2) & 127, ko = (c0 & 3) * 8;
            long src = ((long)b * 128 + crow) * 1024 + j * 512 + it * 32 + ko;
            *(uint4*)&Vt[j][crow][ko] = *(const uint4*)&vt[src];
        }
        __syncthreads();

        // S = Q.K^T (split: QhKh + QhKl + QlKh), 16x32 per wave
        f32x4 s[2];
#pragma unroll
        for (int nt = 0; nt < 2; nt++)
#pragma unroll
            for (int r = 0; r < 4; r++) s[nt][r] = 0.0f;
#pragma unroll
        for (int kc = 0; kc < 4; kc++) {
#pragma unroll
            for (int nt = 0; nt < 2; nt++) {
                bf16x8 bh = *(const bf16x8*)&Kh[g][nt * 16 + l16][kc * 32 + quad * 8];
                bf16x8 bl = *(const bf16x8*)&Kl[g][nt * 16 + l16][kc * 32 + quad * 8];
                s[nt] = MFMA16(qh[kc], bh, s[nt]);
                s[nt] = MFMA16(qh[kc], bl, s[nt]);
                s[nt] = MFMA16(ql[kc], bh, s[nt]);
            }
        }

        // p = exp(s); accumulate per-lane row sums; P -> LDS (C->A layout)
#pragma unroll
        for (int nt = 0; nt < 2; nt++)
#pragma unroll
            for (int r = 0; r < 4; r++) {
                float p = __expf(s[nt][r]);
                lp[r] += p;
                Pl[w][quad * 4 + r][nt * 16 + l16] = f2bf(p);
            }

        // O += P.V (same-wave LDS round-trip; 32-kv chunk = one A-frag)
        bf16x8 pa = *(const bf16x8*)&Pl[w][l16][quad * 8];
#pragma unroll
        for (int t2 = 0; t2 < 8; t2++) {
            bf16x8 vb = *(const bf16x8*)&Vt[g][t2 * 16 + l16][quad * 8];
            o[t2] = MFMA16(pa, vb, o[t2]);
        }
    }

    // reduce lp across the 16 columns
#pragma unroll
    for (int r = 0; r < 4; r++)
#pragma unroll
        for (int off = 1; off < 16; off <<= 1) lp[r] += __shfl_xor(lp[r], off);

    // merge groups via LDS (reuse Kh/Kl as float Ob[4][16][132], Vt as Lb)
    __syncthreads();
    float* Ob = (float*)&Kh[0][0][0];
    float* Lb = (float*)&Vt[0][0][0];
    if (g == 1) {
#pragma unroll
        for (int t2 = 0; t2 < 8; t2++)
#pragma unroll
            for (int r = 0; r < 4; r++)
                Ob[(wsub * 16 + quad * 4 + r) * 132 + t2 * 16 + l16] = o[t2][r];
        if (l16 == 0)
#pragma unroll
            for (int r = 0; r < 4; r++) Lb[wsub * 16 + quad * 4 + r] = lp[r];
    }
    __syncthreads();
    if (g == 0) {
#pragma unroll
        for (int r = 0; r < 4; r++) {
            int lrow = wsub * 16 + quad * 4 + r;
            float inv = 1.0f / (lp[r] + Lb[lrow]);
            long row = (long)b * 4096 + qbase + quad * 4 + r;
#pragma unroll
            for (int t2 = 0; t2 < 8; t2++) {
                float ov = o[t2][r] + Ob[lrow * 132 + t2 * 16 + l16];
                y[row * 128 + t2 * 16 + l16] = f2bf(ov * inv);
            }
        }
    }
}

// ---------------------------------------------------------------------------
// K7: BN statistics: per-channel sum & sumsq over Wy [32768, 256]
// ---------------------------------------------------------------------------
__global__ __launch_bounds__(256) void bnstat_kernel(const float* __restrict__ wy,
                                                     float* __restrict__ acc) {
    int c = threadIdx.x;
    long r0 = (long)blockIdx.x * 32;
    float s = 0.0f, q = 0.0f;
#pragma unroll 4
    for (int i = 0; i < 32; i++) {
        float v = wy[(r0 + i) * 256 + c];
        s += v;
        q += v * v;
    }
    atomicAdd(&acc[c], s);
    atomicAdd(&acc[256 + c], q);
}

// ---------------------------------------------------------------------------
// K8: BN normalize + residual + 2x nearest upsample to NCHW fp32 output.
// ---------------------------------------------------------------------------
__global__ __launch_bounds__(256) void final_kernel(
    const float* __restrict__ wy, const u16* __restrict__ rgbhi,
    const float* __restrict__ acc, const float* __restrict__ gamma,
    const float* __restrict__ beta, float* __restrict__ out) {
    __shared__ float z[16][257];
    int bx = blockIdx.x;
    int wt = bx & 3, h2 = (bx >> 2) & 63, b = bx >> 8;
    int c = threadIdx.x;

    float mean = acc[c] * (1.0f / 32768.0f);
    float var = acc[256 + c] * (1.0f / 32768.0f) - mean * mean;
    float rstd = rsqrtf(var + 1e-5f);
    float gm = gamma[c] * rstd;
    float bt = beta[c] - mean * gm;

    long pbase = (long)b * 4096 + h2 * 64 + wt * 16;
#pragma unroll 4
    for (int i = 0; i < 16; i++) {
        long pi = (pbase + i) * 256 + c;
        z[i][c] = wy[pi] * gm + bt + bf2f(rgbhi[pi]);
    }
    __syncthreads();
    int tid = threadIdx.x;
#pragma unroll 4
    for (int pass = 0; pass < 64; pass++) {
        int cc = pass * 4 + (tid >> 6);
        int r = (tid >> 5) & 1, wc = tid & 31;
        float v = z[wc >> 1][cc];
        out[(((long)b * 256 + cc) * 128 + 2 * h2 + r) * 128 + wt * 32 + wc] = v;
    }
}

// ---------------------------------------------------------------------------
// Workspace layout (bytes), ~115.9 MB with aliasing:
//   rgbpt_hi 0 | rgbpt_lo 16.78M | evpt_hi 33.55M | evpt_lo 50.33M
//   theta_hi 67.11M | theta_lo 75.50M | phiF_hi 83.89M | phiF_lo 92.27M
//   g_full 100.66M | phiK_hi 109.05M | phiK_lo 111.15M | gVt 113.25M
//   wplanes 115.34M | bn acc 115.87M
//   y aliases phiF_hi; Wy (fp32, 33.55M) aliases rgbpt_lo+evpt_hi (both dead)
// ---------------------------------------------------------------------------
extern "C" void kernel_launch(void* const* d_in, const int* in_sizes, int n_in,
                              void* d_out, int out_size, void* d_ws, size_t ws_size,
                              hipStream_t stream) {
    const float* rgb     = (const float*)d_in[0];
    const float* event_  = (const float*)d_in[1];
    const float* g_w     = (const float*)d_in[2];
    const float* g_b     = (const float*)d_in[3];
    const float* theta_w = (const float*)d_in[4];
    const float* theta_b = (const float*)d_in[5];
    const float* phi_w   = (const float*)d_in[6];
    const float* phi_b   = (const float*)d_in[7];
    const float* W_w     = (const float*)d_in[8];
    const float* W_b     = (const float*)d_in[9];
    const float* gamma   = (const float*)d_in[10];
    const float* beta    = (const float*)d_in[11];

    char* ws = (char*)d_ws;
    u16* rgbpt_hi = (u16*)(ws + 0);
    u16* rgbpt_lo = (u16*)(ws + 16777216);
    u16* evpt_hi  = (u16*)(ws + 33554432);
    u16* evpt_lo  = (u16*)(ws + 50331648);
    u16* theta_hi = (u16*)(ws + 67108864);
    u16* theta_lo = (u16*)(ws + 75497472);
    u16* phiF_hi  = (u16*)(ws + 83886080);
    u16* phiF_lo  = (u16*)(ws + 92274688);
    u16* g_full   = (u16*)(ws + 100663296);
    u16* phiK_hi  = (u16*)(ws + 109051904);
    u16* phiK_lo  = (u16*)(ws + 111149056);
    u16* gVt      = (u16*)(ws + 113246208);
    u16* y        = phiF_hi;                      // alias (phiF dead by then)
    float* Wy     = (float*)(ws + 16777216);      // alias rgbpt_lo + evpt_hi
    u16* wplanes  = (u16*)(ws + 115343360);
    float* acc    = (float*)(ws + 115867648);

    zero_kernel<<<2, 256, 0, stream>>>(acc, 512);
    pool_transpose_kernel<<<2048, 256, 0, stream>>>(rgb, rgbpt_hi, rgbpt_lo);
    pool_transpose_kernel<<<2048, 256, 0, stream>>>(event_, evpt_hi, evpt_lo);
    wsplit_kernel<<<512, 256, 0, stream>>>(theta_w, phi_w, g_w, W_w, wplanes);

    // theta = conv(rgb_p), split, hi/lo out; RG=2 -> 128 rows/block, grid 256
    conv1x1_kernel<256, 128, true, 1, 2><<<256, 256, 0, stream>>>(
        rgbpt_hi, rgbpt_lo, wplanes + 0, wplanes + 32768, theta_b,
        theta_hi, theta_lo, nullptr);
    // phi (split) + g (plain) fused over event_p
    conv_phig_kernel<<<256, 256, 0, stream>>>(
        evpt_hi, evpt_lo, wplanes + 65536, wplanes + 98304, wplanes + 131072,
        phi_b, g_b, phiF_hi, phiF_lo, g_full);

    pool_phiK_kernel<<<512, 256, 0, stream>>>(phiF_hi, phiF_lo, phiK_hi, phiK_lo);
    pool_gVt_kernel<<<256, 256, 0, stream>>>(g_full, gVt);

    attn_kernel<<<512, 512, 0, stream>>>(theta_hi, theta_lo, phiK_hi, phiK_lo, gVt, y);

    // W_y = conv(y), fp32 out [B*4096, 256]; RG=1, grid 512
    conv1x1_kernel<128, 256, false, 2, 1><<<512, 256, 0, stream>>>(
        y, nullptr, wplanes + 196608, nullptr, W_b, nullptr, nullptr, Wy);

    bnstat_kernel<<<1024, 256, 0, stream>>>(Wy, acc);
    final_kernel<<<2048, 256, 0, stream>>>(Wy, rgbpt_hi, acc, gamma, beta, (float*)d_out);
}

// Round 3
// 542.701 us; speedup vs baseline: 1.0309x; 1.0309x over previous
//
#include <hip/hip_runtime.h>
#include <stdint.h>

// ---------------------------------------------------------------------------
// LDAM: pooled dual-modality non-local attention + BN + residual + 2x upsample
// B=8, C=256, IC=128 -> pooled 64x64 (Nq=4096), sub-sampled 32x32 (Nkv=1024).
// Round 3: fused pool+transpose+conv kernels (XOR-swizzled 64KB LDS fp32 tile,
// split-bf16 on the fly), BN stats fused into W-conv epilogue, attn unchanged.
// 9 launches total.
// ---------------------------------------------------------------------------

typedef unsigned short u16;
typedef short bf16x8 __attribute__((ext_vector_type(8)));
typedef float f32x4 __attribute__((ext_vector_type(4)));

#define MFMA16(a, b, c) __builtin_amdgcn_mfma_f32_16x16x32_bf16(a, b, c, 0, 0, 0)

__device__ __forceinline__ u16 f2bf(float x) {
    union { float f; unsigned int u; } v; v.f = x;
    unsigned int u = v.u;
    unsigned int r = u + 0x7fffu + ((u >> 16) & 1u);   // round-nearest-even
    return (u16)(r >> 16);
}
__device__ __forceinline__ float bf2f(u16 h) {
    union { unsigned int u; float f; } v; v.u = ((unsigned int)h) << 16;
    return v.f;
}

// ---------------------------------------------------------------------------
// K0: zero the BN accumulator (ws re-poisoned 0xAA before every call)
// ---------------------------------------------------------------------------
__global__ void zero_kernel(float* __restrict__ p, int n) {
    int i = blockIdx.x * 256 + threadIdx.x;
    if (i < n) p[i] = 0.0f;
}

// ---------------------------------------------------------------------------
// K1: split the four weight matrices into bf16 hi/lo planes
// plane m in {theta, phi, g, W}: hi at m*65536, lo at m*65536+32768 (u16 units)
// ---------------------------------------------------------------------------
__global__ void wsplit_kernel(const float* __restrict__ tw, const float* __restrict__ pw,
                              const float* __restrict__ gw, const float* __restrict__ ww,
                              u16* __restrict__ planes) {
    int idx = blockIdx.x * 256 + threadIdx.x;   // 131072 = 4*32768
    int m = idx >> 15, e = idx & 32767;
    const float* src = (m == 0) ? tw : (m == 1) ? pw : (m == 2) ? gw : ww;
    float v = src[e];
    u16 h = f2bf(v);
    planes[m * 65536 + e] = h;
    planes[m * 65536 + 32768 + e] = f2bf(v - bf2f(h));
}

// ---------------------------------------------------------------------------
// K2: fused 2x2 pool + transpose + 1x1 conv (split-bf16 score path).
// Block = one (b, h2) row: A-tile = 64 pooled positions x 256 channels, kept
// in a 64KB fp32 LDS tile, XOR-swizzled by 16B granule: phys col =
// ((c>>2 ^ (row&31))<<2) | (c&3). Pool writes are 2-way-conflict (free);
// A-frag reads are conflict-free b128s.
//   GCONV:  also compute the g conv (plain bf16) sharing the same A.
//   POOLOUT: also store the pooled tile as bf16 hi (residual input).
// grid = B*64 = 512, block = 256 (4 waves x 16 rows).
// ---------------------------------------------------------------------------
template <bool GCONV, bool POOLOUT>
__global__ __launch_bounds__(256) void fused_pool_conv_kernel(
    const float* __restrict__ x,
    const u16* __restrict__ W1h, const u16* __restrict__ W1l,
    const float* __restrict__ b1,
    const u16* __restrict__ W2h, const float* __restrict__ b2,
    u16* __restrict__ o1_hi, u16* __restrict__ o1_lo, u16* __restrict__ o2,
    u16* __restrict__ pool_hi) {
    __shared__ float Pt[64 * 256];   // swizzled [w2][c], 65536 B

    int bx = blockIdx.x;
    int b = bx >> 6, h2 = bx & 63;
    int tid = threadIdx.x;

    // ---- phase 1: load fp32 NCHW, 2x2 max pool, scatter into swizzled LDS
    long ibase = (long)b * 256 * 16384 + (long)(2 * h2) * 128;
#pragma unroll 8
    for (int i = 0; i < 32; i++) {
        int u = i * 256 + tid;
        int c = u >> 5, w4 = u & 31;
        const float* p = &x[ibase + (long)c * 16384 + w4 * 4];
        float4 r0 = *(const float4*)p;
        float4 r1 = *(const float4*)(p + 128);
        float p0 = fmaxf(fmaxf(r0.x, r0.y), fmaxf(r1.x, r1.y));
        float p1 = fmaxf(fmaxf(r0.z, r0.w), fmaxf(r1.z, r1.w));
        int row0 = 2 * w4, row1 = 2 * w4 + 1;
        Pt[row0 * 256 + (((((c >> 2)) ^ (row0 & 31)) << 2) | (c & 3))] = p0;
        Pt[row1 * 256 + (((((c >> 2)) ^ (row1 & 31)) << 2) | (c & 3))] = p1;
    }
    __syncthreads();

    // ---- phase 2: MFMA conv(s)
    int wave = tid >> 6, lane = tid & 63, quad = lane >> 4, l16 = lane & 15;
    int arow = wave * 16 + l16;                 // 0..63 block-local position

    f32x4 a1[8];
    f32x4 a2[GCONV ? 8 : 1];
#pragma unroll
    for (int nt = 0; nt < 8; nt++) {
#pragma unroll
        for (int r = 0; r < 4; r++) a1[nt][r] = 0.0f;
        if (GCONV)
#pragma unroll
            for (int r = 0; r < 4; r++) a2[nt][r] = 0.0f;
    }

#pragma unroll
    for (int kc = 0; kc < 8; kc++) {
        int g0 = kc * 8 + quad * 2;             // 16B granule index (4 floats)
        float4 fA = *(const float4*)&Pt[arow * 256 + ((g0 ^ (arow & 31)) << 2)];
        float4 fB = *(const float4*)&Pt[arow * 256 + (((g0 + 1) ^ (arow & 31)) << 2)];
        float vv[8] = {fA.x, fA.y, fA.z, fA.w, fB.x, fB.y, fB.z, fB.w};
        bf16x8 ah, al;
#pragma unroll
        for (int e = 0; e < 8; e++) {
            u16 h = f2bf(vv[e]);
            ah[e] = (short)h;
            al[e] = (short)f2bf(vv[e] - bf2f(h));
        }
#pragma unroll
        for (int nt = 0; nt < 8; nt++) {
            long wrow = (long)(nt * 16 + l16) * 256 + kc * 32 + quad * 8;
            bf16x8 bh = *(const bf16x8*)&W1h[wrow];
            bf16x8 bl = *(const bf16x8*)&W1l[wrow];
            a1[nt] = MFMA16(ah, bh, a1[nt]);
            a1[nt] = MFMA16(ah, bl, a1[nt]);
            a1[nt] = MFMA16(al, bh, a1[nt]);
            if (GCONV) {
                bf16x8 bg = *(const bf16x8*)&W2h[wrow];
                a2[nt] = MFMA16(ah, bg, a2[nt]);
            }
        }
    }

    // ---- epilogue: C/D layout (col = l16 tile, row = quad*4+r), [pos][128]
    long mbase = (long)b * 4096 + h2 * 64;
#pragma unroll
    for (int nt = 0; nt < 8; nt++) {
        int colo = nt * 16 + l16;
        float bv1 = b1[colo];
        float bv2 = GCONV ? b2[colo] : 0.0f;
#pragma unroll
        for (int r = 0; r < 4; r++) {
            long row = mbase + wave * 16 + quad * 4 + r;
            long idx = row * 128 + colo;
            float v = a1[nt][r] + bv1;
            u16 h = f2bf(v);
            o1_hi[idx] = h;
            o1_lo[idx] = f2bf(v - bf2f(h));
            if (GCONV) o2[idx] = f2bf(a2[nt][r] + bv2);
        }
    }

    // ---- pooled-x bf16 store for the residual ([pos][256])
    if (POOLOUT) {
#pragma unroll 4
        for (int i = 0; i < 32; i++) {
            int r = i * 2 + (tid >> 7);
            int c = (tid & 127) * 2;
            int g = c >> 2;
            float2 f = *(const float2*)&Pt[r * 256 + (((g ^ (r & 31)) << 2) | (c & 3))];
            ushort2 hh;
            hh.x = f2bf(f.x);
            hh.y = f2bf(f.y);
            *(ushort2*)&pool_hi[(mbase + r) * 256 + c] = hh;
        }
    }
}

// ---------------------------------------------------------------------------
// K3: sub-sample pool phi -> K layout [B,1024,128] hi/lo, vectorized bf16x8.
// ---------------------------------------------------------------------------
__global__ __launch_bounds__(256) void pool_phiK_kernel(
    const u16* __restrict__ fhi, const u16* __restrict__ flo,
    u16* __restrict__ khi, u16* __restrict__ klo) {
    int idx = blockIdx.x * 256 + threadIdx.x;   // 131072 = 8*1024*16
    int c8 = (idx & 15) * 8;
    int kv = (idx >> 4) & 1023;
    int b = idx >> 14;
    int h4 = kv >> 5, w4 = kv & 31;
    long p00 = ((long)b * 4096 + (2 * h4) * 64 + 2 * w4) * 128 + c8;
    bf16x8 h0 = *(const bf16x8*)&fhi[p00];
    bf16x8 h1 = *(const bf16x8*)&fhi[p00 + 128];
    bf16x8 h2 = *(const bf16x8*)&fhi[p00 + 8192];
    bf16x8 h3 = *(const bf16x8*)&fhi[p00 + 8320];
    bf16x8 l0 = *(const bf16x8*)&flo[p00];
    bf16x8 l1 = *(const bf16x8*)&flo[p00 + 128];
    bf16x8 l2 = *(const bf16x8*)&flo[p00 + 8192];
    bf16x8 l3 = *(const bf16x8*)&flo[p00 + 8320];
    bf16x8 oh, ol;
#pragma unroll
    for (int e = 0; e < 8; e++) {
        float v = fmaxf(fmaxf(bf2f((u16)h0[e]) + bf2f((u16)l0[e]),
                              bf2f((u16)h1[e]) + bf2f((u16)l1[e])),
                        fmaxf(bf2f((u16)h2[e]) + bf2f((u16)l2[e]),
                              bf2f((u16)h3[e]) + bf2f((u16)l3[e])));
        u16 h = f2bf(v);
        oh[e] = (short)h;
        ol[e] = (short)f2bf(v - bf2f(h));
    }
    long oi = ((long)b * 1024 + kv) * 128 + c8;
    *(bf16x8*)&khi[oi] = oh;
    *(bf16x8*)&klo[oi] = ol;
}

// ---------------------------------------------------------------------------
// K4: sub-sample pool g + transpose -> V^T [B,128,1024] bf16
// ---------------------------------------------------------------------------
__global__ __launch_bounds__(256) void pool_gVt_kernel(
    const u16* __restrict__ g, u16* __restrict__ vt) {
    __shared__ u16 t[64][65];   // [c_l][kv_l]
    int bx = blockIdx.x;
    int ct = bx & 1, kvt = (bx >> 1) & 15, b = bx >> 5;
    int tid = threadIdx.x;
#pragma unroll 4
    for (int i = 0; i < 16; i++) {
        int idx = i * 256 + tid;
        int kv_l = idx >> 6, c_l = idx & 63;
        int kv = kvt * 64 + kv_l;
        int h4 = kv >> 5, w4 = kv & 31;
        long p00 = ((long)b * 4096 + (2 * h4) * 64 + 2 * w4) * 128 + ct * 64 + c_l;
        float v = fmaxf(fmaxf(bf2f(g[p00]), bf2f(g[p00 + 128])),
                        fmaxf(bf2f(g[p00 + 8192]), bf2f(g[p00 + 8192 + 128])));
        t[c_l][kv_l] = f2bf(v);
    }
    __syncthreads();
    long ob = ((long)b * 128 + ct * 64) * 1024 + kvt * 64;
#pragma unroll 4
    for (int i = 0; i < 16; i++) {
        int idx = i * 256 + tid;
        int c_l = idx >> 6, kv_l = idx & 63;
        vt[ob + (long)c_l * 1024 + kv_l] = t[c_l][kv_l];
    }
}

// ---------------------------------------------------------------------------
// K5: fused attention, NO-MAX softmax (scores max ~23 -> exp fits fp32/bf16;
// partials over disjoint KV merge by pure addition). 512 threads = 8 waves:
// waves 0-3 take kv [0,512), waves 4-7 take [512,1024) for the same 64 Q
// rows; merge via LDS. KV tile 32/group, LDS = 64 KB -> 2 blocks/CU.
// ---------------------------------------------------------------------------
__global__ __launch_bounds__(512, 4) void attn_kernel(
    const u16* __restrict__ th, const u16* __restrict__ tl,
    const u16* __restrict__ khi, const u16* __restrict__ klo,
    const u16* __restrict__ vt, u16* __restrict__ y) {
    __shared__ u16 Kh[2][32][136];   // 17408 B
    __shared__ u16 Kl[2][32][136];   // 17408 B
    __shared__ u16 Vt[2][128][40];   // 20480 B
    __shared__ u16 Pl[8][16][40];    // 10240 B   => 65536 B total

    int bx = blockIdx.x;
    int b = bx & 7, qt = bx >> 3;
    int tid = threadIdx.x;
    int w = tid >> 6, g = w >> 2, wsub = w & 3;
    int lane = tid & 63, quad = lane >> 4, l16 = lane & 15;
    int qbase = qt * 64 + wsub * 16;

    bf16x8 qh[4], ql[4];
    long tb = ((long)b * 4096 + qbase + l16) * 128;
#pragma unroll
    for (int kc = 0; kc < 4; kc++) {
        qh[kc] = *(const bf16x8*)&th[tb + kc * 32 + quad * 8];
        ql[kc] = *(const bf16x8*)&tl[tb + kc * 32 + quad * 8];
    }

    f32x4 o[8];
#pragma unroll
    for (int t2 = 0; t2 < 8; t2++)
#pragma unroll
        for (int r = 0; r < 4; r++) o[t2][r] = 0.0f;
    float lp[4] = {0.0f, 0.0f, 0.0f, 0.0f};

#pragma unroll 1
    for (int it = 0; it < 16; it++) {
        __syncthreads();
#pragma unroll
        for (int j = 0; j < 2; j++) {
            int c0 = j * 512 + tid;
            int row = (c0 >> 4) & 31, ko = (c0 & 15) * 8;
            long src = ((long)b * 1024 + j * 512 + it * 32 + row) * 128 + ko;
            *(uint4*)&Kh[j][row][ko] = *(const uint4*)&khi[src];
            *(uint4*)&Kl[j][row][ko] = *(const uint4*)&klo[src];
        }
#pragma unroll
        for (int j = 0; j < 2; j++) {
            int c0 = j * 512 + tid;
            int crow = (c0 >> 2) & 127, ko = (c0 & 3) * 8;
            long src = ((long)b * 128 + crow) * 1024 + j * 512 + it * 32 + ko;
            *(uint4*)&Vt[j][crow][ko] = *(const uint4*)&vt[src];
        }
        __syncthreads();

        f32x4 s[2];
#pragma unroll
        for (int nt = 0; nt < 2; nt++)
#pragma unroll
            for (int r = 0; r < 4; r++) s[nt][r] = 0.0f;
#pragma unroll
        for (int kc = 0; kc < 4; kc++) {
#pragma unroll
            for (int nt = 0; nt < 2; nt++) {
                bf16x8 bh = *(const bf16x8*)&Kh[g][nt * 16 + l16][kc * 32 + quad * 8];
                bf16x8 bl = *(const bf16x8*)&Kl[g][nt * 16 + l16][kc * 32 + quad * 8];
                s[nt] = MFMA16(qh[kc], bh, s[nt]);
                s[nt] = MFMA16(qh[kc], bl, s[nt]);
                s[nt] = MFMA16(ql[kc], bh, s[nt]);
            }
        }

#pragma unroll
        for (int nt = 0; nt < 2; nt++)
#pragma unroll
            for (int r = 0; r < 4; r++) {
                float p = __expf(s[nt][r]);
                lp[r] += p;
                Pl[w][quad * 4 + r][nt * 16 + l16] = f2bf(p);
            }

        bf16x8 pa = *(const bf16x8*)&Pl[w][l16][quad * 8];
#pragma unroll
        for (int t2 = 0; t2 < 8; t2++) {
            bf16x8 vb = *(const bf16x8*)&Vt[g][t2 * 16 + l16][quad * 8];
            o[t2] = MFMA16(pa, vb, o[t2]);
        }
    }

#pragma unroll
    for (int r = 0; r < 4; r++)
#pragma unroll
        for (int off = 1; off < 16; off <<= 1) lp[r] += __shfl_xor(lp[r], off);

    __syncthreads();
    float* Ob = (float*)&Kh[0][0][0];
    float* Lb = (float*)&Vt[0][0][0];
    if (g == 1) {
#pragma unroll
        for (int t2 = 0; t2 < 8; t2++)
#pragma unroll
            for (int r = 0; r < 4; r++)
                Ob[(wsub * 16 + quad * 4 + r) * 132 + t2 * 16 + l16] = o[t2][r];
        if (l16 == 0)
#pragma unroll
            for (int r = 0; r < 4; r++) Lb[wsub * 16 + quad * 4 + r] = lp[r];
    }
    __syncthreads();
    if (g == 0) {
#pragma unroll
        for (int r = 0; r < 4; r++) {
            int lrow = wsub * 16 + quad * 4 + r;
            float inv = 1.0f / (lp[r] + Lb[lrow]);
            long row = (long)b * 4096 + qbase + quad * 4 + r;
#pragma unroll
            for (int t2 = 0; t2 < 8; t2++) {
                float ov = o[t2][r] + Ob[lrow * 132 + t2 * 16 + l16];
                y[row * 128 + t2 * 16 + l16] = f2bf(ov * inv);
            }
        }
    }
}

// ---------------------------------------------------------------------------
// K6: W conv (K=128, O=256, plain bf16, fp32 out) + fused BN statistics.
// Per-wave column sums via cross-quad shuffles, cross-wave via LDS, then one
// atomicAdd per channel per block. grid = 512, block = 256.
// ---------------------------------------------------------------------------
__global__ __launch_bounds__(256) void wconv_kernel(
    const u16* __restrict__ A, const u16* __restrict__ Wh,
    const float* __restrict__ bias, float* __restrict__ out_f,
    float* __restrict__ acc_g) {
    __shared__ float red[4][2][256];
    int tid = threadIdx.x;
    int wave = tid >> 6, lane = tid & 63, quad = lane >> 4, l16 = lane & 15;
    long mbase = (long)blockIdx.x * 64 + wave * 16;

    f32x4 acc[16];
#pragma unroll
    for (int nt = 0; nt < 16; nt++)
#pragma unroll
        for (int r = 0; r < 4; r++) acc[nt][r] = 0.0f;

#pragma unroll
    for (int kc = 0; kc < 4; kc++) {
        bf16x8 ah = *(const bf16x8*)&A[(mbase + l16) * 128 + kc * 32 + quad * 8];
#pragma unroll
        for (int nt = 0; nt < 16; nt++) {
            bf16x8 bh = *(const bf16x8*)&Wh[(long)(nt * 16 + l16) * 128 + kc * 32 + quad * 8];
            acc[nt] = MFMA16(ah, bh, acc[nt]);
        }
    }

#pragma unroll
    for (int nt = 0; nt < 16; nt++) {
        int colo = nt * 16 + l16;
        float bv = bias[colo];
        float vs = 0.0f, vq = 0.0f;
#pragma unroll
        for (int r = 0; r < 4; r++) {
            long row = mbase + quad * 4 + r;
            float v = acc[nt][r] + bv;
            out_f[row * 256 + colo] = v;
            vs += v;
            vq += v * v;
        }
        vs += __shfl_xor(vs, 16); vs += __shfl_xor(vs, 32);
        vq += __shfl_xor(vq, 16); vq += __shfl_xor(vq, 32);
        if (quad == 0) {
            red[wave][0][colo] = vs;
            red[wave][1][colo] = vq;
        }
    }
    __syncthreads();
    if (tid < 256) {
        int c = tid;
        float s = red[0][0][c] + red[1][0][c] + red[2][0][c] + red[3][0][c];
        float q = red[0][1][c] + red[1][1][c] + red[2][1][c] + red[3][1][c];
        atomicAdd(&acc_g[c], s);
        atomicAdd(&acc_g[256 + c], q);
    }
}

// ---------------------------------------------------------------------------
// K7: BN normalize + residual + 2x nearest upsample to NCHW fp32 output.
// ---------------------------------------------------------------------------
__global__ __launch_bounds__(256) void final_kernel(
    const float* __restrict__ wy, const u16* __restrict__ rgbhi,
    const float* __restrict__ acc, const float* __restrict__ gamma,
    const float* __restrict__ beta, float* __restrict__ out) {
    __shared__ float z[16][257];
    int bx = blockIdx.x;
    int wt = bx & 3, h2 = (bx >> 2) & 63, b = bx >> 8;
    int c = threadIdx.x;

    float mean = acc[c] * (1.0f / 32768.0f);
    float var = acc[256 + c] * (1.0f / 32768.0f) - mean * mean;
    float rstd = rsqrtf(var + 1e-5f);
    float gm = gamma[c] * rstd;
    float bt = beta[c] - mean * gm;

    long pbase = (long)b * 4096 + h2 * 64 + wt * 16;
#pragma unroll 4
    for (int i = 0; i < 16; i++) {
        long pi = (pbase + i) * 256 + c;
        z[i][c] = wy[pi] * gm + bt + bf2f(rgbhi[pi]);
    }
    __syncthreads();
    int tid = threadIdx.x;
#pragma unroll 4
    for (int pass = 0; pass < 64; pass++) {
        int cc = pass * 4 + (tid >> 6);
        int r = (tid >> 5) & 1, wc = tid & 31;
        float v = z[wc >> 1][cc];
        out[(((long)b * 256 + cc) * 128 + 2 * h2 + r) * 128 + wt * 32 + wc] = v;
    }
}

// ---------------------------------------------------------------------------
// Workspace layout (bytes), ~107.5 MB, no aliasing:
//   rgbpt_hi 0 (16.78M) | theta_hi 16.78M | theta_lo 25.17M | phiF_hi 33.55M
//   phiF_lo 41.94M | g_full 50.33M | phiK_hi 58.72M | phiK_lo 60.82M
//   gVt 62.91M | y 65.01M | Wy 73.40M (fp32 33.55M) | wplanes 106.95M
//   acc 107.48M
// ---------------------------------------------------------------------------
extern "C" void kernel_launch(void* const* d_in, const int* in_sizes, int n_in,
                              void* d_out, int out_size, void* d_ws, size_t ws_size,
                              hipStream_t stream) {
    const float* rgb     = (const float*)d_in[0];
    const float* event_  = (const float*)d_in[1];
    const float* g_w     = (const float*)d_in[2];
    const float* g_b     = (const float*)d_in[3];
    const float* theta_w = (const float*)d_in[4];
    const float* theta_b = (const float*)d_in[5];
    const float* phi_w   = (const float*)d_in[6];
    const float* phi_b   = (const float*)d_in[7];
    const float* W_w     = (const float*)d_in[8];
    const float* W_b     = (const float*)d_in[9];
    const float* gamma   = (const float*)d_in[10];
    const float* beta    = (const float*)d_in[11];

    char* ws = (char*)d_ws;
    u16* rgbpt_hi = (u16*)(ws + 0);
    u16* theta_hi = (u16*)(ws + 16777216);
    u16* theta_lo = (u16*)(ws + 25165824);
    u16* phiF_hi  = (u16*)(ws + 33554432);
    u16* phiF_lo  = (u16*)(ws + 41943040);
    u16* g_full   = (u16*)(ws + 50331648);
    u16* phiK_hi  = (u16*)(ws + 58720256);
    u16* phiK_lo  = (u16*)(ws + 60817408);
    u16* gVt      = (u16*)(ws + 62914560);
    u16* y        = (u16*)(ws + 65011712);
    float* Wy     = (float*)(ws + 73400320);
    u16* wplanes  = (u16*)(ws + 106954752);
    float* acc    = (float*)(ws + 107479040);

    zero_kernel<<<2, 256, 0, stream>>>(acc, 512);
    wsplit_kernel<<<512, 256, 0, stream>>>(theta_w, phi_w, g_w, W_w, wplanes);

    // rgb path: pool + theta conv (split) + rgbpt_hi store
    fused_pool_conv_kernel<false, true><<<512, 256, 0, stream>>>(
        rgb, wplanes + 0, wplanes + 32768, theta_b,
        nullptr, nullptr, theta_hi, theta_lo, nullptr, rgbpt_hi);
    // event path: pool + phi conv (split) + g conv (plain)
    fused_pool_conv_kernel<true, false><<<512, 256, 0, stream>>>(
        event_, wplanes + 65536, wplanes + 98304, phi_b,
        wplanes + 131072, g_b, phiF_hi, phiF_lo, g_full, nullptr);

    pool_phiK_kernel<<<512, 256, 0, stream>>>(phiF_hi, phiF_lo, phiK_hi, phiK_lo);
    pool_gVt_kernel<<<256, 256, 0, stream>>>(g_full, gVt);

    attn_kernel<<<512, 512, 0, stream>>>(theta_hi, theta_lo, phiK_hi, phiK_lo, gVt, y);

    // W conv + fused BN stats
    wconv_kernel<<<512, 256, 0, stream>>>(y, wplanes + 196608, W_b, Wy, acc);

    final_kernel<<<2048, 256, 0, stream>>>(Wy, rgbpt_hi, acc, gamma, beta, (float*)d_out);
}